// Round 10
// baseline (152.885 us; speedup 1.0000x reference)
//
#include <hip/hip_runtime.h>
#include <math.h>

#define NP 8192
#define NF 16384
#define SPLIT 16
#define NFS (NF / SPLIT)   // faces per split = 1024
#define PB  256            // points per block (= block size)
#define NPB (NP / PB)      // point blocks = 32

// ---------------------------------------------------------------------------
// K0: face centers in f64 + |c|^2 (np: c=(v0+v1+v2)/3), plus Adagrad clr table
// ---------------------------------------------------------------------------
__global__ __launch_bounds__(256) void k_centers(const float* __restrict__ mV,
                                                 const int* __restrict__ mF,
                                                 double* __restrict__ ctr,
                                                 double* __restrict__ clrtab) {
    if (blockIdx.x == 0 && threadIdx.x < 50) {
        clrtab[threadIdx.x] = 0.2 / (1.0 + (double)threadIdx.x * 0.1);
    }
    int f = blockIdx.x * 256 + threadIdx.x;
    if (f >= NF) return;
    int i0 = mF[3*f+0], i1 = mF[3*f+1], i2 = mF[3*f+2];
    double cx = ((double)mV[3*i0+0] + (double)mV[3*i1+0] + (double)mV[3*i2+0]) / 3.0;
    double cy = ((double)mV[3*i0+1] + (double)mV[3*i1+1] + (double)mV[3*i2+1]) / 3.0;
    double cz = ((double)mV[3*i0+2] + (double)mV[3*i1+2] + (double)mV[3*i2+2]) / 3.0;
    ctr[4*f+0] = cx; ctr[4*f+1] = cy; ctr[4*f+2] = cz;
    ctr[4*f+3] = cx*cx + cy*cy + cz*cz;
}

// ---------------------------------------------------------------------------
// K1a: partial f64 1-NN, TRANSPOSED ownership: one THREAD = one point (q in
// 6 VGPR, best/idx in 3 — spill impossible by construction, unlike rounds
// 5-9 where the allocator kept dumping the 24 block-uniform q-doubles to
// scratch). The face stream is block-uniform: every thread scans the same
// ascending face sequence, so ctr4[f] has a wave-uniform address ->
// scalarizable to s_load (SMEM pipe) or an L1 broadcast.
// key = cc - 2 q.c (bit-identical formula); within-thread strict < over
// ascending f == lex (key,idx); partials merged ascending-split in k_finish
// (the proven round-5/8 pattern) -> outputs provably identical.
// ---------------------------------------------------------------------------
__global__ __launch_bounds__(256) void k_knn_part(const float* __restrict__ qV,
                                                  const double* __restrict__ ctr,
                                                  double* __restrict__ pkey,
                                                  int* __restrict__ pidx) {
    int g = blockIdx.x / SPLIT;          // point group
    int s = blockIdx.x % SPLIT;          // face split
    int p = g * PB + threadIdx.x;        // this thread's point

    double qx = (double)qV[3*p+0];
    double qy = (double)qV[3*p+1];
    double qz = (double)qV[3*p+2];
    double best = 1e300; int bi = 0x7fffffff;

    const double4* ctr4 = (const double4*)ctr;
    int fbase = s * NFS;
    #pragma unroll 4
    for (int i = 0; i < NFS; ++i) {
        int f = fbase + i;               // block-uniform
        double4 c = ctr4[f];             // wave-uniform address
        double dot = qx*c.x + qy*c.y + qz*c.z;
        double key = c.w - 2.0*dot;
        if (key < best) { best = key; bi = f; }  // f ascends: strict < = lex
    }
    pkey[(size_t)s*NP + p] = best;       // split-major: coalesced write+read
    pidx[(size_t)s*NP + p] = bi;
}

// ---------------------------------------------------------------------------
// K1b: per point, lex-merge the SPLIT partials (ascending s), exact np d2
// for the winner, outlier test, final fidx/mask outputs.
// ---------------------------------------------------------------------------
__global__ __launch_bounds__(256) void k_finish(const float* __restrict__ qV,
                                                const double* __restrict__ ctr,
                                                const double* __restrict__ pkey,
                                                const int* __restrict__ pidx,
                                                float* __restrict__ out,
                                                int* __restrict__ fidx_ws,
                                                int* __restrict__ valid_ws) {
    int p = blockIdx.x * 256 + threadIdx.x;
    if (p >= NP) return;
    double bv = 1e300; int bi = 0x7fffffff;
    #pragma unroll
    for (int s = 0; s < SPLIT; ++s) {
        double ov = pkey[(size_t)s*NP + p];
        int    oi = pidx[(size_t)s*NP + p];
        if (ov < bv || (ov == bv && oi < bi)) { bv = ov; bi = oi; }
    }
    // exact np d2 for the winning face
    const double4* ctr4 = (const double4*)ctr;
    double4 c = ctr4[bi];
    double qx = (double)qV[3*p+0], qy = (double)qV[3*p+1], qz = (double)qV[3*p+2];
    double dot = qx*c.x + qy*c.y + qz*c.z;
    double qq  = qx*qx + qy*qy + qz*qz;
    double d2  = (qq - 2.0*dot) + c.w;
    int outlier = (d2 > 0.1) ? 1 : 0;
    fidx_ws[p]  = bi;
    valid_ws[p] = 1 - outlier;
    out[p]        = (float)bi;               // output 0: spt_fidx
    out[3*NP + p] = outlier ? 1.0f : 0.0f;   // output 2: outlier_mask
}

// ---------------------------------------------------------------------------
// K2: denom = max(#valid, 1)
// ---------------------------------------------------------------------------
__global__ __launch_bounds__(256) void k_denom(const int* __restrict__ valid_ws,
                                               double* __restrict__ denom) {
    __shared__ int s[256];
    int acc = 0;
    for (int i = threadIdx.x; i < NP; i += 256) acc += valid_ws[i];
    s[threadIdx.x] = acc;
    __syncthreads();
    for (int off = 128; off > 0; off >>= 1) {
        if (threadIdx.x < off) s[threadIdx.x] += s[threadIdx.x + off];
        __syncthreads();
    }
    if (threadIdx.x == 0) {
        double d = (double)s[0];
        denom[0] = d > 1.0 ? d : 1.0;
    }
}

// ---------------------------------------------------------------------------
// K3: per-point 2x50-step Adagrad — BIT-IDENTICAL to the round-4 passing
// version (slim vw margin; do not perturb).
// ---------------------------------------------------------------------------
__global__ __launch_bounds__(256) void k_opt(const float* __restrict__ qV,
                                             const float* __restrict__ qN,
                                             const float* __restrict__ mV,
                                             const int* __restrict__ mF,
                                             const float* __restrict__ mN,
                                             const int* __restrict__ fidx_ws,
                                             const int* __restrict__ valid_ws,
                                             const double* __restrict__ denomp,
                                             const double* __restrict__ clrtab,
                                             float* __restrict__ out) {
    int p = blockIdx.x * 256 + threadIdx.x;
    if (p >= NP) return;
    const float third = (float)(1.0/3.0);
    if (!valid_ws[p]) {            // outlier: keeps init barycentric coords
        out[NP + 2*p + 0] = third;
        out[NP + 2*p + 1] = third;
        return;
    }
    double inv_denom = 1.0 / denomp[0];
    int f = fidx_ws[p];
    int i0 = mF[3*f+0], i1 = mF[3*f+1], i2 = mF[3*f+2];

    double V0x = mV[3*i0+0], V0y = mV[3*i0+1], V0z = mV[3*i0+2];
    double V1x = mV[3*i1+0], V1y = mV[3*i1+1], V1z = mV[3*i1+2];
    double V2x = mV[3*i2+0], V2y = mV[3*i2+1], V2z = mV[3*i2+2];
    double N0x = mN[3*i0+0], N0y = mN[3*i0+1], N0z = mN[3*i0+2];
    double N1x = mN[3*i1+0], N1y = mN[3*i1+1], N1z = mN[3*i1+2];
    double N2x = mN[3*i2+0], N2y = mN[3*i2+1], N2z = mN[3*i2+2];
    double qx  = qV[3*p+0],  qy  = qV[3*p+1],  qz  = qV[3*p+2];
    double qnx = qN[3*p+0],  qny = qN[3*p+1],  qnz = qN[3*p+2];

    double Eux = V0x - V2x, Euy = V0y - V2y, Euz = V0z - V2z;  // dcV/du
    double Ewx = V1x - V2x, Ewy = V1y - V2y, Ewz = V1z - V2z;  // dcV/dw
    double Fux = N0x - N2x, Fuy = N0y - N2y, Fuz = N0z - N2z;  // dn_raw/du
    double Fwx = N1x - N2x, Fwy = N1y - N2y, Fwz = N1z - N2z;  // dn_raw/dw
    double Kx  = V2x - qx,  Ky  = V2y - qy,  Kz  = V2z - qz;   // cv - q at uu=ww=0

    double u = 1.0/3.0, w = 1.0/3.0;
    double alpha = 1.0;
    for (int outer = 0; outer < 2; ++outer) {
        double du = 0.0, dw = 0.0, su = 0.0, sw = 0.0;
        for (int it = 0; it < 50; ++it) {
            double uu = u + du, ww = w + dw;
            // position term: rv = cv - q = uu*Eu + ww*Ew + K
            double rvx = uu*Eux + ww*Ewx + Kx;
            double rvy = uu*Euy + ww*Ewy + Ky;
            double rvz = uu*Euz + ww*Ewz + Kz;
            double L2v = rvx*rvx + rvy*rvy + rvz*rvz;
            double invLv = rsqrt(L2v);
            double gu = (rvx*Eux + rvy*Euy + rvz*Euz) * invLv;
            double gw = (rvx*Ewx + rvy*Ewy + rvz*Ewz) * invLv;
            // normal term: n = uu*Fu + ww*Fw + N2
            double nx = uu*Fux + ww*Fwx + N2x;
            double ny = uu*Fuy + ww*Fwy + N2y;
            double nz = uu*Fuz + ww*Fwz + N2z;
            double m2 = nx*nx + ny*ny + nz*nz;
            bool   mok = (m2 > 1e-24);           // <=> m > 1e-12
            double inv = mok ? rsqrt(m2) : 1e12; // 1/max(m,1e-12)
            double hx = nx*inv, hy = ny*inv, hz = nz*inv;
            double rnx = hx - qnx, rny = hy - qny, rnz = hz - qnz;
            double L2n = rnx*rnx + rny*rny + rnz*rnz;
            double invLn = rsqrt(L2n);
            double A_u = rnx*Fux + rny*Fuy + rnz*Fuz;
            double A_w = rnx*Fwx + rny*Fwy + rnz*Fwz;
            double B   = rnx*nx + rny*ny + rnz*nz;
            double C_u = nx*Fux + ny*Fuy + nz*Fuz;
            double C_w = nx*Fwx + ny*Fwy + nz*Fwz;
            // s = B/m^3 when m > eps else 0 (original dropped the term there)
            double s = mok ? ((B*inv)*inv)*inv : 0.0;
            double gnu = (A_u*inv - s*C_u) * invLn;
            double gnw = (A_w*inv - s*C_w) * invLn;
            gu = (gu + 0.01*gnu) * inv_denom;   // mask=1, masked-mean scaling
            gw = (gw + 0.01*gnw) * inv_denom;
            // Adagrad(lr=0.2, lr_decay=0.1)
            su += gu*gu; sw += gw*gw;
            double clr = clrtab[it];
            du -= clr * gu / (sqrt(su) + 1e-10);
            dw -= clr * gw / (sqrt(sw) + 1e-10);
        }
        u += du * alpha; w += dw * alpha;
        alpha *= 0.5;
    }
    out[NP + 2*p + 0] = (float)u;
    out[NP + 2*p + 1] = (float)w;
}

// ---------------------------------------------------------------------------
extern "C" void kernel_launch(void* const* d_in, const int* in_sizes, int n_in,
                              void* d_out, int out_size, void* d_ws, size_t ws_size,
                              hipStream_t stream) {
    const float* qV = (const float*)d_in[0];   // query_V [1,8192,3]
    const float* qN = (const float*)d_in[1];   // query_N [1,8192,3]
    const float* mV = (const float*)d_in[2];   // mesh_V  [16384,3]
    const int*   mF = (const int*)d_in[3];     // mesh_F  [16384,3] int32
    const float* mN = (const float*)d_in[4];   // mesh_N  [16384,3]
    float* out = (float*)d_out;                // fidx | vw | outlier_mask

    double* ctr      = (double*)d_ws;               // NF*4 doubles (512 KB)
    double* denom    = ctr + (size_t)NF*4;          // 1 double
    double* clrtab   = denom + 1;                   // 50 doubles
    double* pkey     = clrtab + 50;                 // SPLIT*NP doubles (1 MB)
    int*    pidx     = (int*)(pkey + (size_t)SPLIT*NP);  // SPLIT*NP ints (512 KB)
    int*    fidx_ws  = pidx + (size_t)SPLIT*NP;          // NP ints
    int*    valid_ws = fidx_ws + NP;                     // NP ints

    hipLaunchKernelGGL(k_centers,  dim3(NF/256),    dim3(256), 0, stream, mV, mF, ctr, clrtab);
    hipLaunchKernelGGL(k_knn_part, dim3(NPB*SPLIT), dim3(256), 0, stream, qV, ctr, pkey, pidx);
    hipLaunchKernelGGL(k_finish,   dim3(NP/256),    dim3(256), 0, stream, qV, ctr, pkey, pidx,
                       out, fidx_ws, valid_ws);
    hipLaunchKernelGGL(k_denom,    dim3(1),         dim3(256), 0, stream, valid_ws, denom);
    hipLaunchKernelGGL(k_opt,      dim3(NP/256),    dim3(256), 0, stream,
                       qV, qN, mV, mF, mN, fidx_ws, valid_ws, denom, clrtab, out);
}

// Round 11
// 99.415 us; speedup vs baseline: 1.5378x; 1.5378x over previous
//
#include <hip/hip_runtime.h>
#include <math.h>

#define NP 8192
#define NF 16384
#define GQ 8

// ---------------------------------------------------------------------------
// K0: face centers in f64 + |c|^2 (np: c=(v0+v1+v2)/3), plus Adagrad clr table
// ---------------------------------------------------------------------------
__global__ __launch_bounds__(256) void k_centers(const float* __restrict__ mV,
                                                 const int* __restrict__ mF,
                                                 double* __restrict__ ctr,
                                                 double* __restrict__ clrtab) {
    if (blockIdx.x == 0 && threadIdx.x < 50) {
        clrtab[threadIdx.x] = 0.2 / (1.0 + (double)threadIdx.x * 0.1);
    }
    int f = blockIdx.x * 256 + threadIdx.x;
    if (f >= NF) return;
    int i0 = mF[3*f+0], i1 = mF[3*f+1], i2 = mF[3*f+2];
    double cx = ((double)mV[3*i0+0] + (double)mV[3*i1+0] + (double)mV[3*i2+0]) / 3.0;
    double cy = ((double)mV[3*i0+1] + (double)mV[3*i1+1] + (double)mV[3*i2+1]) / 3.0;
    double cz = ((double)mV[3*i0+2] + (double)mV[3*i1+2] + (double)mV[3*i2+2]) / 3.0;
    ctr[4*f+0] = cx; ctr[4*f+1] = cy; ctr[4*f+2] = cz;
    ctr[4*f+3] = cx*cx + cy*cy + cz*cz;
}

// ---------------------------------------------------------------------------
// K1: brute-force 1-NN — EXACT round-3 kernel (the fastest knn measured this
// session, ~46 µs inferred; every restructuring since lost to it).
// key = cc - 2 q.c (monotone in d2); winner's true d2 recomputed with np's
// association (qq - 2 dot) + cc; lex (key,idx) == jnp.argmin tie-break.
// ---------------------------------------------------------------------------
__global__ __launch_bounds__(256) void k_knn(const float* __restrict__ qV,
                                             const double* __restrict__ ctr,
                                             float* __restrict__ out,
                                             int* __restrict__ fidx_ws,
                                             int* __restrict__ valid_ws) {
    int pbase = blockIdx.x * GQ;
    double qx[GQ], qy[GQ], qz[GQ];
    #pragma unroll
    for (int g = 0; g < GQ; ++g) {
        int p = pbase + g;
        qx[g] = (double)qV[3*p+0];
        qy[g] = (double)qV[3*p+1];
        qz[g] = (double)qV[3*p+2];
    }
    double best[GQ]; int bidx[GQ];
    #pragma unroll
    for (int g = 0; g < GQ; ++g) { best[g] = 1e300; bidx[g] = 0x7fffffff; }

    const double4* ctr4 = (const double4*)ctr;
    #pragma unroll 2
    for (int f = threadIdx.x; f < NF; f += 256) {
        double4 c = ctr4[f];
        #pragma unroll
        for (int g = 0; g < GQ; ++g) {
            double dot = qx[g]*c.x + qy[g]*c.y + qz[g]*c.z;
            double key = c.w - 2.0*dot;
            if (key < best[g]) { best[g] = key; bidx[g] = f; }  // f ascends: < = lex
        }
    }
    // wave (64-lane) reduction, lexicographic (key, idx)
    #pragma unroll
    for (int off = 32; off > 0; off >>= 1) {
        #pragma unroll
        for (int g = 0; g < GQ; ++g) {
            double ov = __shfl_down(best[g], off);
            int    oi = __shfl_down(bidx[g], off);
            if (ov < best[g] || (ov == best[g] && oi < bidx[g])) { best[g] = ov; bidx[g] = oi; }
        }
    }
    __shared__ double sv[4][GQ];
    __shared__ int    si[4][GQ];
    int wid = threadIdx.x >> 6, lane = threadIdx.x & 63;
    if (lane == 0) {
        #pragma unroll
        for (int g = 0; g < GQ; ++g) { sv[wid][g] = best[g]; si[wid][g] = bidx[g]; }
    }
    __syncthreads();
    if (threadIdx.x == 0) {
        for (int g = 0; g < GQ; ++g) {
            double bv = sv[0][g]; int bi = si[0][g];
            for (int w2 = 1; w2 < 4; ++w2) {
                double ov = sv[w2][g]; int oi = si[w2][g];
                if (ov < bv || (ov == bv && oi < bi)) { bv = ov; bi = oi; }
            }
            int p = pbase + g;
            // exact np d2 for the winning face
            double4 c = ctr4[bi];
            double dot = qx[g]*c.x + qy[g]*c.y + qz[g]*c.z;
            double qq  = qx[g]*qx[g] + qy[g]*qy[g] + qz[g]*qz[g];
            double d2  = (qq - 2.0*dot) + c.w;
            int outlier = (d2 > 0.1) ? 1 : 0;
            fidx_ws[p]  = bi;
            valid_ws[p] = 1 - outlier;
            out[p]          = (float)bi;              // output 0: spt_fidx
            out[3*NP + p]   = outlier ? 1.0f : 0.0f;  // output 2: outlier_mask
        }
    }
}

// ---------------------------------------------------------------------------
// K2: denom = max(#valid, 1)
// ---------------------------------------------------------------------------
__global__ __launch_bounds__(256) void k_denom(const int* __restrict__ valid_ws,
                                               double* __restrict__ denom) {
    __shared__ int s[256];
    int acc = 0;
    for (int i = threadIdx.x; i < NP; i += 256) acc += valid_ws[i];
    s[threadIdx.x] = acc;
    __syncthreads();
    for (int off = 128; off > 0; off >>= 1) {
        if (threadIdx.x < off) s[threadIdx.x] += s[threadIdx.x + off];
        __syncthreads();
    }
    if (threadIdx.x == 0) {
        double d = (double)s[0];
        denom[0] = d > 1.0 ? d : 1.0;
    }
}

// ---------------------------------------------------------------------------
// K3: per-point 2x50-step Adagrad — BIT-IDENTICAL to the round-4 passing
// version (slim vw margin; do not perturb).
// ---------------------------------------------------------------------------
__global__ __launch_bounds__(256) void k_opt(const float* __restrict__ qV,
                                             const float* __restrict__ qN,
                                             const float* __restrict__ mV,
                                             const int* __restrict__ mF,
                                             const float* __restrict__ mN,
                                             const int* __restrict__ fidx_ws,
                                             const int* __restrict__ valid_ws,
                                             const double* __restrict__ denomp,
                                             const double* __restrict__ clrtab,
                                             float* __restrict__ out) {
    int p = blockIdx.x * 256 + threadIdx.x;
    if (p >= NP) return;
    const float third = (float)(1.0/3.0);
    if (!valid_ws[p]) {            // outlier: keeps init barycentric coords
        out[NP + 2*p + 0] = third;
        out[NP + 2*p + 1] = third;
        return;
    }
    double inv_denom = 1.0 / denomp[0];
    int f = fidx_ws[p];
    int i0 = mF[3*f+0], i1 = mF[3*f+1], i2 = mF[3*f+2];

    double V0x = mV[3*i0+0], V0y = mV[3*i0+1], V0z = mV[3*i0+2];
    double V1x = mV[3*i1+0], V1y = mV[3*i1+1], V1z = mV[3*i1+2];
    double V2x = mV[3*i2+0], V2y = mV[3*i2+1], V2z = mV[3*i2+2];
    double N0x = mN[3*i0+0], N0y = mN[3*i0+1], N0z = mN[3*i0+2];
    double N1x = mN[3*i1+0], N1y = mN[3*i1+1], N1z = mN[3*i1+2];
    double N2x = mN[3*i2+0], N2y = mN[3*i2+1], N2z = mN[3*i2+2];
    double qx  = qV[3*p+0],  qy  = qV[3*p+1],  qz  = qV[3*p+2];
    double qnx = qN[3*p+0],  qny = qN[3*p+1],  qnz = qN[3*p+2];

    double Eux = V0x - V2x, Euy = V0y - V2y, Euz = V0z - V2z;  // dcV/du
    double Ewx = V1x - V2x, Ewy = V1y - V2y, Ewz = V1z - V2z;  // dcV/dw
    double Fux = N0x - N2x, Fuy = N0y - N2y, Fuz = N0z - N2z;  // dn_raw/du
    double Fwx = N1x - N2x, Fwy = N1y - N2y, Fwz = N1z - N2z;  // dn_raw/dw
    double Kx  = V2x - qx,  Ky  = V2y - qy,  Kz  = V2z - qz;   // cv - q at uu=ww=0

    double u = 1.0/3.0, w = 1.0/3.0;
    double alpha = 1.0;
    for (int outer = 0; outer < 2; ++outer) {
        double du = 0.0, dw = 0.0, su = 0.0, sw = 0.0;
        for (int it = 0; it < 50; ++it) {
            double uu = u + du, ww = w + dw;
            // position term: rv = cv - q = uu*Eu + ww*Ew + K
            double rvx = uu*Eux + ww*Ewx + Kx;
            double rvy = uu*Euy + ww*Ewy + Ky;
            double rvz = uu*Euz + ww*Ewz + Kz;
            double L2v = rvx*rvx + rvy*rvy + rvz*rvz;
            double invLv = rsqrt(L2v);
            double gu = (rvx*Eux + rvy*Euy + rvz*Euz) * invLv;
            double gw = (rvx*Ewx + rvy*Ewy + rvz*Ewz) * invLv;
            // normal term: n = uu*Fu + ww*Fw + N2
            double nx = uu*Fux + ww*Fwx + N2x;
            double ny = uu*Fuy + ww*Fwy + N2y;
            double nz = uu*Fuz + ww*Fwz + N2z;
            double m2 = nx*nx + ny*ny + nz*nz;
            bool   mok = (m2 > 1e-24);           // <=> m > 1e-12
            double inv = mok ? rsqrt(m2) : 1e12; // 1/max(m,1e-12)
            double hx = nx*inv, hy = ny*inv, hz = nz*inv;
            double rnx = hx - qnx, rny = hy - qny, rnz = hz - qnz;
            double L2n = rnx*rnx + rny*rny + rnz*rnz;
            double invLn = rsqrt(L2n);
            double A_u = rnx*Fux + rny*Fuy + rnz*Fuz;
            double A_w = rnx*Fwx + rny*Fwy + rnz*Fwz;
            double B   = rnx*nx + rny*ny + rnz*nz;
            double C_u = nx*Fux + ny*Fuy + nz*Fuz;
            double C_w = nx*Fwx + ny*Fwy + nz*Fwz;
            // s = B/m^3 when m > eps else 0 (original dropped the term there)
            double s = mok ? ((B*inv)*inv)*inv : 0.0;
            double gnu = (A_u*inv - s*C_u) * invLn;
            double gnw = (A_w*inv - s*C_w) * invLn;
            gu = (gu + 0.01*gnu) * inv_denom;   // mask=1, masked-mean scaling
            gw = (gw + 0.01*gnw) * inv_denom;
            // Adagrad(lr=0.2, lr_decay=0.1)
            su += gu*gu; sw += gw*gw;
            double clr = clrtab[it];
            du -= clr * gu / (sqrt(su) + 1e-10);
            dw -= clr * gw / (sqrt(sw) + 1e-10);
        }
        u += du * alpha; w += dw * alpha;
        alpha *= 0.5;
    }
    out[NP + 2*p + 0] = (float)u;
    out[NP + 2*p + 1] = (float)w;
}

// ---------------------------------------------------------------------------
extern "C" void kernel_launch(void* const* d_in, const int* in_sizes, int n_in,
                              void* d_out, int out_size, void* d_ws, size_t ws_size,
                              hipStream_t stream) {
    const float* qV = (const float*)d_in[0];   // query_V [1,8192,3]
    const float* qN = (const float*)d_in[1];   // query_N [1,8192,3]
    const float* mV = (const float*)d_in[2];   // mesh_V  [16384,3]
    const int*   mF = (const int*)d_in[3];     // mesh_F  [16384,3] int32
    const float* mN = (const float*)d_in[4];   // mesh_N  [16384,3]
    float* out = (float*)d_out;                // fidx | vw | outlier_mask

    double* ctr      = (double*)d_ws;          // NF*4 doubles (cx,cy,cz,|c|^2)
    double* denom    = ctr + (size_t)NF*4;     // 1 double
    double* clrtab   = denom + 1;              // 50 doubles
    int*    fidx_ws  = (int*)(clrtab + 50);    // NP ints
    int*    valid_ws = fidx_ws + NP;           // NP ints

    hipLaunchKernelGGL(k_centers, dim3(NF/256), dim3(256), 0, stream, mV, mF, ctr, clrtab);
    hipLaunchKernelGGL(k_knn,     dim3(NP/GQ),  dim3(256), 0, stream, qV, ctr, out, fidx_ws, valid_ws);
    hipLaunchKernelGGL(k_denom,   dim3(1),      dim3(256), 0, stream, valid_ws, denom);
    hipLaunchKernelGGL(k_opt,     dim3(NP/256), dim3(256), 0, stream,
                       qV, qN, mV, mF, mN, fidx_ws, valid_ws, denom, clrtab, out);
}